// Round 5
// baseline (154.213 us; speedup 1.0000x reference)
//
#include <hip/hip_runtime.h>
#include <hip/hip_bf16.h>
#include <math.h>

#define NB 2
#define C 256
#define P 4096   // 64*64
#define EPS_F 1e-5f

typedef __attribute__((ext_vector_type(8))) short short8;
typedef __attribute__((ext_vector_type(4))) float f32x4;

__device__ __forceinline__ float bf2f(unsigned short u) {
    union { unsigned int i; float f; } x;
    x.i = ((unsigned int)u) << 16;
    return x.f;
}

// ---------------- K1: per-channel mean of featureT over n,h,w ----------------
__global__ void k_mean(const float* __restrict__ fT, float* __restrict__ mean) {
    int c = blockIdx.x;
    int t = threadIdx.x;
    const float* p0 = fT + (size_t)c * P;          // n=0
    const float* p1 = fT + (size_t)(C + c) * P;    // n=1
    float s = 0.f;
    for (int i = t; i < P; i += 256) s += p0[i] + p1[i];
    __shared__ float red[256];
    red[t] = s; __syncthreads();
    for (int o = 128; o > 0; o >>= 1) { if (t < o) red[t] += red[t + o]; __syncthreads(); }
    if (t == 0) mean[c] = red[0] * (1.f / 8192.f);
}

// ---------------- K2: per-pixel 1/||x - mean|| ----------------
__global__ void k_norm(const float* __restrict__ f, const float* __restrict__ mean,
                       float* __restrict__ rnorm) {
    __shared__ float mn[C];
    __shared__ float part[4][64];
    int t = threadIdx.x;
    mn[t] = mean[t];
    __syncthreads();
    int n = blockIdx.y;
    int p0 = blockIdx.x * 64;
    int pl = t & 63, cg = t >> 6;
    const float* base = f + (size_t)n * C * P + p0 + pl;
    float acc = 0.f;
    #pragma unroll 4
    for (int cc = 0; cc < 64; cc++) {
        int c = cg * 64 + cc;
        float v = base[(size_t)c * P] - mn[c];
        acc += v * v;
    }
    part[cg][pl] = acc;
    __syncthreads();
    if (t < 64) {
        float s = part[0][t] + part[1][t] + part[2][t] + part[3][t];
        rnorm[n * P + p0 + t] = rsqrtf(s);
    }
}

// ---------------- K3: transpose NCHW -> [n][p][c], center+scale, cast bf16 ----------------
__global__ void k_pack(const float* __restrict__ f, const float* __restrict__ mean,
                       const float* __restrict__ rnorm, __hip_bfloat16* __restrict__ out) {
    __shared__ float tile[64][65];
    int t = threadIdx.x;
    int n = blockIdx.z, c0 = blockIdx.y * 64, p0 = blockIdx.x * 64;
    const float* base = f + ((size_t)n * C + c0) * P + p0;
    #pragma unroll
    for (int i = 0; i < 16; i++) {
        int idx = t + 256 * i;
        int cc = idx >> 6, pp = idx & 63;
        tile[cc][pp] = base[(size_t)cc * P + pp] - mean[c0 + cc];
    }
    __syncthreads();
    #pragma unroll
    for (int i = 0; i < 16; i++) {
        int idx = t + 256 * i;
        int pp = idx >> 6, cc = idx & 63;
        float v = tile[cc][pp] * rnorm[n * P + p0 + pp];
        out[(size_t)(n * P + p0 + pp) * C + c0 + cc] = __float2bfloat16(v);
    }
}

// ---------------- staging: one wave stages 32 rows x 32 cols (64B/row) of a tile ----------------
// LDS layout: linear [128 rows][64 B]. Source pre-swizzled by ((row>>1)&3)<<4 so the
// swizzled ds_read_b128 below hits 8 distinct 16B slots per consecutive 8 lanes.
__device__ __forceinline__ void stage_tile(const __hip_bfloat16* __restrict__ gbase,
                                           __hip_bfloat16* lbuf, int kk, int wid, int lane) {
    #pragma unroll
    for (int j = 0; j < 2; j++) {
        int row = wid * 32 + j * 16 + (lane >> 2);
        int cb = (lane & 3) * 16;
        int scb = cb ^ (((row >> 1) & 3) << 4);
        const char* gp = (const char*)gbase + (size_t)row * (C * 2) + kk * 64 + scb;
        char* lp = (char*)lbuf + (wid * 32 + j * 16) * 64;   // wave-uniform base
        __builtin_amdgcn_global_load_lds(
            (const __attribute__((address_space(1))) void*)gp,
            (__attribute__((address_space(3))) void*)lp, 16, 0, 0);
    }
}

__device__ __forceinline__ short8 ldfrag(const __hip_bfloat16* lbuf, int rloc, int kb) {
    int addr = rloc * 64 + (kb ^ (((rloc >> 1) & 3) << 4));
    return *(const short8*)((const char*)lbuf + addr);
}

// ---------------- K4: fused GEMM: bf16 dist store (LDS-transposed) + row-max partials ----------------
__global__ __launch_bounds__(256) void k_gemm(const __hip_bfloat16* __restrict__ TI,
                                              const __hip_bfloat16* __restrict__ TT,
                                              __hip_bfloat16* __restrict__ D,
                                              float* __restrict__ Mpart) {
    // grid: x = p-tile(32), y = q-tile(32), z = n(2); 4 waves 2x2 over 128x128, BK=32
    __shared__ char smem[32768];
    int lane = threadIdx.x & 63, wid = threadIdx.x >> 6;
    int wr = wid >> 1, wc = wid & 1;
    int n = blockIdx.z;
    const __hip_bfloat16* A = TI + ((size_t)n * P + blockIdx.y * 128) * C;
    const __hip_bfloat16* B = TT + ((size_t)n * P + blockIdx.x * 128) * C;

    f32x4 acc[4][4];
    #pragma unroll
    for (int m = 0; m < 4; m++)
        #pragma unroll
        for (int nt = 0; nt < 4; nt++)
            acc[m][nt] = (f32x4){0.f, 0.f, 0.f, 0.f};

    int rA = lane & 15;
    int kb = (lane >> 4) * 16;   // byte offset within 64B k-row

    stage_tile(A, (__hip_bfloat16*)smem, 0, wid, lane);
    stage_tile(B, (__hip_bfloat16*)(smem + 16384), 0, wid, lane);
    __syncthreads();

    #pragma unroll
    for (int t = 0; t < 8; t++) {
        int cur = t & 1;
        __hip_bfloat16* lAc = (__hip_bfloat16*)(smem + cur * 8192);
        __hip_bfloat16* lBc = (__hip_bfloat16*)(smem + 16384 + cur * 8192);
        if (t < 7) {
            stage_tile(A, (__hip_bfloat16*)(smem + (cur ^ 1) * 8192), t + 1, wid, lane);
            stage_tile(B, (__hip_bfloat16*)(smem + 16384 + (cur ^ 1) * 8192), t + 1, wid, lane);
        }
        short8 a[4], b[4];
        #pragma unroll
        for (int m = 0; m < 4; m++)
            a[m] = ldfrag(lAc, wr * 64 + m * 16 + rA, kb);
        #pragma unroll
        for (int nt = 0; nt < 4; nt++)
            b[nt] = ldfrag(lBc, wc * 64 + nt * 16 + rA, kb);
        #pragma unroll
        for (int m = 0; m < 4; m++)
            #pragma unroll
            for (int nt = 0; nt < 4; nt++)
                acc[m][nt] = __builtin_amdgcn_mfma_f32_16x16x32_bf16(a[m], b[nt], acc[m][nt], 0, 0, 0);
        __syncthreads();
    }

    // epilogue 1: acc -> LDS as 128x128 bf16, then coalesced 16B global stores
    __hip_bfloat16* tbuf = (__hip_bfloat16*)smem;
    int rj = (lane >> 4) * 4, cl = lane & 15;
    #pragma unroll
    for (int m = 0; m < 4; m++)
        #pragma unroll
        for (int nt = 0; nt < 4; nt++)
            #pragma unroll
            for (int j = 0; j < 4; j++)
                tbuf[(wr * 64 + m * 16 + rj + j) * 128 + wc * 64 + nt * 16 + cl] =
                    __float2bfloat16(acc[m][nt][j]);
    __syncthreads();
    {
        int t = threadIdx.x;
        int row = t >> 1, cseg = (t & 1) * 64;
        int qb0 = blockIdx.y * 128, pb0 = blockIdx.x * 128;
        const short8* src = (const short8*)(tbuf + row * 128 + cseg);
        __hip_bfloat16* dst = D + (size_t)n * P * P + (size_t)(qb0 + row) * P + pb0 + cseg;
        #pragma unroll
        for (int i = 0; i < 8; i++)
            *(short8*)(dst + i * 8) = src[i];
    }

    // epilogue 2: row-max partials (exact, fp32)
    int qb = blockIdx.y * 128 + wr * 64;
    int pt = blockIdx.x * 2 + wc;
    #pragma unroll
    for (int m = 0; m < 4; m++) {
        f32x4 mx = acc[m][0];
        #pragma unroll
        for (int nt = 1; nt < 4; nt++)
            #pragma unroll
            for (int j = 0; j < 4; j++)
                mx[j] = fmaxf(mx[j], acc[m][nt][j]);
        #pragma unroll
        for (int j = 0; j < 4; j++)
            #pragma unroll
            for (int o = 1; o < 16; o <<= 1)
                mx[j] = fmaxf(mx[j], __shfl_xor(mx[j], o));
        if ((lane & 15) == 0) {
            int qbase = qb + m * 16 + (lane >> 4) * 4;
            #pragma unroll
            for (int j = 0; j < 4; j++)
                Mpart[((size_t)(n * P + qbase + j)) * 64 + pt] = mx[j];
        }
    }
}

// ---------------- reduce M -> t2, md ----------------
__global__ void k_redM(const float* __restrict__ Mpart, float* __restrict__ t2a,
                       float* __restrict__ mda) {
    int row = blockIdx.x * 256 + threadIdx.x;  // 0..8191
    const f32x4* src = (const f32x4*)(Mpart + (size_t)row * 64);
    float m = -1e30f;
    #pragma unroll
    for (int i = 0; i < 16; i++) {
        f32x4 v = src[i];
        m = fmaxf(m, fmaxf(fmaxf(v[0], v[1]), fmaxf(v[2], v[3])));
    }
    mda[row] = m;
    t2a[row] = 5.f / ((1.f - m) * 0.5f + EPS_F);
}

// ---------------- K5: fused Z + colmax partials (single pass over D) ----------------
__global__ __launch_bounds__(256) void k_zcol(const __hip_bfloat16* __restrict__ D,
                                              const float* __restrict__ t2a,
                                              const float* __restrict__ mda,
                                              float* __restrict__ Cpart) {
    // grid: x = row-group (256 groups of 16 rows), y = n; block 256
    __shared__ __hip_bfloat16 tile[4][P];   // 32 KiB: 4 rows staged at a time
    __shared__ float sZ[4], st2[4], smd[4];
    int t = threadIdx.x, lane = t & 63, w = t >> 6;
    int n = blockIdx.y, g = blockIdx.x;
    float cmax[16];
    #pragma unroll
    for (int i = 0; i < 16; i++) cmax[i] = 0.f;

    for (int c = 0; c < 4; c++) {
        int row = g * 16 + c * 4 + w;   // wave w stages & reduces row w of this chunk
        const char* gsrc = (const char*)(D + ((size_t)n * P + row) * P);
        char* ldst = (char*)&tile[w][0];
        #pragma unroll
        for (int i = 0; i < 8; i++)
            __builtin_amdgcn_global_load_lds(
                (const __attribute__((address_space(1))) void*)(gsrc + i * 1024 + lane * 16),
                (__attribute__((address_space(3))) void*)(ldst + i * 1024), 16, 0, 0);
        float t2 = t2a[n * P + row], md = mda[n * P + row];
        __syncthreads();
        // Z phase: wave w reduces its own row
        float z = 0.f;
        const short8* trow = (const short8*)&tile[w][0];
        #pragma unroll
        for (int i = 0; i < 8; i++) {
            short8 v = trow[lane + 64 * i];
            #pragma unroll
            for (int j = 0; j < 8; j++)
                z += __expf(t2 * (bf2f((unsigned short)v[j]) - md));
        }
        #pragma unroll
        for (int o = 32; o > 0; o >>= 1) z += __shfl_xor(z, o);
        if (lane == 0) { sZ[w] = z; st2[w] = t2; smd[w] = md; }
        __syncthreads();
        // colmax phase: thread t owns cols [t*8, t*8+8) and [2048+t*8, ...)
        float rz0 = 1.f / sZ[0], rz1 = 1.f / sZ[1], rz2 = 1.f / sZ[2], rz3 = 1.f / sZ[3];
        float lrz[4] = {rz0, rz1, rz2, rz3};
        #pragma unroll
        for (int h = 0; h < 2; h++) {
            int cb = h * 2048 + t * 8;
            #pragma unroll
            for (int r = 0; r < 4; r++) {
                short8 v = *(const short8*)&tile[r][cb];
                float tt = st2[r], mm = smd[r], zz = lrz[r];
                #pragma unroll
                for (int j = 0; j < 8; j++) {
                    float val = __expf(tt * (bf2f((unsigned short)v[j]) - mm)) * zz;
                    cmax[h * 8 + j] = fmaxf(cmax[h * 8 + j], val);
                }
            }
        }
        __syncthreads();   // before restaging tile
    }
    float* cp = Cpart + ((size_t)(n * 256 + g)) * P;
    #pragma unroll
    for (int h = 0; h < 2; h++) {
        f32x4 v0 = {cmax[h*8+0], cmax[h*8+1], cmax[h*8+2], cmax[h*8+3]};
        f32x4 v1 = {cmax[h*8+4], cmax[h*8+5], cmax[h*8+6], cmax[h*8+7]};
        *(f32x4*)(cp + h * 2048 + t * 8) = v0;
        *(f32x4*)(cp + h * 2048 + t * 8 + 4) = v1;
    }
}

// ---------------- reduce colmax partials ----------------
__global__ void k_colred(const float* __restrict__ Cpart, float* __restrict__ colmax) {
    int np = blockIdx.x * 256 + threadIdx.x;  // flat n*P+p, 0..8191
    int n = np >> 12, p = np & 4095;
    float c = 0.f;
    for (int g = 0; g < 256; g++)
        c = fmaxf(c, Cpart[((size_t)(n * 256 + g)) * P + p]);
    colmax[np] = c;
}

// ---------------- final: -log(mean_p colmax), mean over n ----------------
__global__ void k_final(const float* __restrict__ colmax, float* __restrict__ out) {
    __shared__ float red[256];
    int t = threadIdx.x;
    float cx[NB];
    for (int n = 0; n < NB; n++) {
        float s = 0.f;
        for (int i = t; i < P; i += 256) s += colmax[n * P + i];
        red[t] = s; __syncthreads();
        for (int o = 128; o > 0; o >>= 1) { if (t < o) red[t] += red[t + o]; __syncthreads(); }
        cx[n] = -logf(red[0] * (1.f / (float)P));
        __syncthreads();
    }
    if (t == 0) out[0] = 0.5f * (cx[0] + cx[1]);
}

extern "C" void kernel_launch(void* const* d_in, const int* in_sizes, int n_in,
                              void* d_out, int out_size, void* d_ws, size_t ws_size,
                              hipStream_t stream) {
    const float* fT = (const float*)d_in[0];   // featureT
    const float* fI = (const float*)d_in[1];   // featureI
    float* out = (float*)d_out;

    char* ws = (char*)d_ws;
    size_t off = 0;
    __hip_bfloat16* TI = (__hip_bfloat16*)(ws + off); off += 4194304;
    __hip_bfloat16* TT = (__hip_bfloat16*)(ws + off); off += 4194304;
    __hip_bfloat16* D  = (__hip_bfloat16*)(ws + off); off += (size_t)NB * P * P * 2;  // 67 MiB
    float* Mpart  = (float*)(ws + off); off += (size_t)NB * P * 64 * 4;               // 2 MiB
    float* Cpart  = (float*)(ws + off); off += (size_t)NB * 256 * P * 4;              // 8 MiB
    float* mean   = (float*)(ws + off); off += 1024;
    float* rnormI = (float*)(ws + off); off += 32768;
    float* rnormT = (float*)(ws + off); off += 32768;
    float* t2a    = (float*)(ws + off); off += 32768;
    float* mda    = (float*)(ws + off); off += 32768;
    float* colmax = (float*)(ws + off); off += 32768;

    k_mean<<<256, 256, 0, stream>>>(fT, mean);
    k_norm<<<dim3(64, 2), 256, 0, stream>>>(fI, mean, rnormI);
    k_norm<<<dim3(64, 2), 256, 0, stream>>>(fT, mean, rnormT);
    k_pack<<<dim3(64, 4, 2), 256, 0, stream>>>(fI, mean, rnormI, TI);
    k_pack<<<dim3(64, 4, 2), 256, 0, stream>>>(fT, mean, rnormT, TT);
    k_gemm<<<dim3(32, 32, 2), 256, 0, stream>>>(TI, TT, D, Mpart);
    k_redM<<<32, 256, 0, stream>>>(Mpart, t2a, mda);
    k_zcol<<<dim3(256, 2), 256, 0, stream>>>(D, t2a, mda, Cpart);
    k_colred<<<32, 256, 0, stream>>>(Cpart, colmax);
    k_final<<<1, 256, 0, stream>>>(colmax, out);
}

// Round 7
// 117.816 us; speedup vs baseline: 1.3089x; 1.3089x over previous
//
#include <hip/hip_runtime.h>
#include <hip/hip_bf16.h>
#include <math.h>

#define NB 2
#define C 256
#define P 4096   // 64*64
#define EPS_F 1e-5f

typedef __attribute__((ext_vector_type(8))) short short8;
typedef __attribute__((ext_vector_type(4))) float f32x4;

__device__ __forceinline__ float bf2f(unsigned short u) {
    union { unsigned int i; float f; } x;
    x.i = ((unsigned int)u) << 16;
    return x.f;
}

// ---------------- K1: per-channel mean of featureT over n,h,w ----------------
__global__ void k_mean(const float* __restrict__ fT, float* __restrict__ mean) {
    int c = blockIdx.x;
    int t = threadIdx.x;
    const float* p0 = fT + (size_t)c * P;          // n=0
    const float* p1 = fT + (size_t)(C + c) * P;    // n=1
    float s = 0.f;
    for (int i = t; i < P; i += 256) s += p0[i] + p1[i];
    __shared__ float red[256];
    red[t] = s; __syncthreads();
    for (int o = 128; o > 0; o >>= 1) { if (t < o) red[t] += red[t + o]; __syncthreads(); }
    if (t == 0) mean[c] = red[0] * (1.f / 8192.f);
}

// ---------------- K2: per-pixel 1/||x - mean|| ----------------
__global__ void k_norm(const float* __restrict__ f, const float* __restrict__ mean,
                       float* __restrict__ rnorm) {
    __shared__ float mn[C];
    __shared__ float part[4][64];
    int t = threadIdx.x;
    mn[t] = mean[t];
    __syncthreads();
    int n = blockIdx.y;
    int p0 = blockIdx.x * 64;
    int pl = t & 63, cg = t >> 6;
    const float* base = f + (size_t)n * C * P + p0 + pl;
    float acc = 0.f;
    #pragma unroll 4
    for (int cc = 0; cc < 64; cc++) {
        int c = cg * 64 + cc;
        float v = base[(size_t)c * P] - mn[c];
        acc += v * v;
    }
    part[cg][pl] = acc;
    __syncthreads();
    if (t < 64) {
        float s = part[0][t] + part[1][t] + part[2][t] + part[3][t];
        rnorm[n * P + p0 + t] = rsqrtf(s);
    }
}

// ---------------- K3: transpose NCHW -> [n][p][c], center+scale, cast bf16 ----------------
__global__ void k_pack(const float* __restrict__ f, const float* __restrict__ mean,
                       const float* __restrict__ rnorm, __hip_bfloat16* __restrict__ out) {
    __shared__ float tile[64][65];
    int t = threadIdx.x;
    int n = blockIdx.z, c0 = blockIdx.y * 64, p0 = blockIdx.x * 64;
    const float* base = f + ((size_t)n * C + c0) * P + p0;
    #pragma unroll
    for (int i = 0; i < 16; i++) {
        int idx = t + 256 * i;
        int cc = idx >> 6, pp = idx & 63;
        tile[cc][pp] = base[(size_t)cc * P + pp] - mean[c0 + cc];
    }
    __syncthreads();
    #pragma unroll
    for (int i = 0; i < 16; i++) {
        int idx = t + 256 * i;
        int pp = idx >> 6, cc = idx & 63;
        float v = tile[cc][pp] * rnorm[n * P + p0 + pp];
        out[(size_t)(n * P + p0 + pp) * C + c0 + cc] = __float2bfloat16(v);
    }
}

// ---------------- staging: one wave stages 32 rows x 32 cols (64B/row) of a tile ----------------
// LDS layout: linear [128 rows][64 B]. Source pre-swizzled by ((row>>1)&3)<<4 so the
// swizzled ds_read_b128 below hits all 8 distinct 16B slots per consecutive 8 lanes
// (2 lanes/slot = conflict-free per m136).
__device__ __forceinline__ void stage_tile(const __hip_bfloat16* __restrict__ gbase,
                                           __hip_bfloat16* lbuf, int kk, int wid, int lane) {
    #pragma unroll
    for (int j = 0; j < 2; j++) {
        int row = wid * 32 + j * 16 + (lane >> 2);
        int cb = (lane & 3) * 16;
        int scb = cb ^ (((row >> 1) & 3) << 4);
        const char* gp = (const char*)gbase + (size_t)row * (C * 2) + kk * 64 + scb;
        char* lp = (char*)lbuf + (wid * 32 + j * 16) * 64;   // wave-uniform base
        __builtin_amdgcn_global_load_lds(
            (const __attribute__((address_space(1))) void*)gp,
            (__attribute__((address_space(3))) void*)lp, 16, 0, 0);
    }
}

__device__ __forceinline__ short8 ldfrag(const __hip_bfloat16* lbuf, int rloc, int kb) {
    int addr = rloc * 64 + (kb ^ (((rloc >> 1) & 3) << 4));
    return *(const short8*)((const char*)lbuf + addr);
}

// ---------------- K4: fused GEMM: bf16 dist store + row-max partials ----------------
__global__ __launch_bounds__(256) void k_gemm(const __hip_bfloat16* __restrict__ TI,
                                              const __hip_bfloat16* __restrict__ TT,
                                              __hip_bfloat16* __restrict__ D,
                                              float* __restrict__ Mpart) {
    // grid: x = p-tile(32), y = q-tile(32), z = n(2); 4 waves 2x2 over 128x128, BK=32
    __shared__ __hip_bfloat16 lA[2][128 * 32];
    __shared__ __hip_bfloat16 lB[2][128 * 32];
    int lane = threadIdx.x & 63, wid = threadIdx.x >> 6;
    int wr = wid >> 1, wc = wid & 1;
    int n = blockIdx.z;
    const __hip_bfloat16* A = TI + ((size_t)n * P + blockIdx.y * 128) * C;
    const __hip_bfloat16* B = TT + ((size_t)n * P + blockIdx.x * 128) * C;

    f32x4 acc[4][4];
    #pragma unroll
    for (int m = 0; m < 4; m++)
        #pragma unroll
        for (int nt = 0; nt < 4; nt++)
            acc[m][nt] = (f32x4){0.f, 0.f, 0.f, 0.f};

    int rA = lane & 15;
    int kb = (lane >> 4) * 16;   // byte offset within 64B k-row

    stage_tile(A, lA[0], 0, wid, lane);
    stage_tile(B, lB[0], 0, wid, lane);
    __syncthreads();

    #pragma unroll
    for (int t = 0; t < 8; t++) {
        int cur = t & 1;
        if (t < 7) {
            stage_tile(A, lA[cur ^ 1], t + 1, wid, lane);
            stage_tile(B, lB[cur ^ 1], t + 1, wid, lane);
        }
        short8 a[4], b[4];
        #pragma unroll
        for (int m = 0; m < 4; m++)
            a[m] = ldfrag(lA[cur], wr * 64 + m * 16 + rA, kb);
        #pragma unroll
        for (int nt = 0; nt < 4; nt++)
            b[nt] = ldfrag(lB[cur], wc * 64 + nt * 16 + rA, kb);
        #pragma unroll
        for (int m = 0; m < 4; m++)
            #pragma unroll
            for (int nt = 0; nt < 4; nt++)
                acc[m][nt] = __builtin_amdgcn_mfma_f32_16x16x32_bf16(a[m], b[nt], acc[m][nt], 0, 0, 0);
        __syncthreads();
    }

    // epilogue 1: bf16 dist store (direct, fragment-layout scalar stores)
    int qb = blockIdx.y * 128 + wr * 64;
    int pb = blockIdx.x * 128 + wc * 64;
    int rj = (lane >> 4) * 4, cl = lane & 15;
    __hip_bfloat16* Dn = D + (size_t)n * P * P;
    #pragma unroll
    for (int m = 0; m < 4; m++)
        #pragma unroll
        for (int nt = 0; nt < 4; nt++)
            #pragma unroll
            for (int j = 0; j < 4; j++)
                Dn[(size_t)(qb + m * 16 + rj + j) * P + pb + nt * 16 + cl] =
                    __float2bfloat16(acc[m][nt][j]);

    // epilogue 2: row-max partials (exact, fp32)
    int pt = blockIdx.x * 2 + wc;
    #pragma unroll
    for (int m = 0; m < 4; m++) {
        f32x4 mx = acc[m][0];
        #pragma unroll
        for (int nt = 1; nt < 4; nt++)
            #pragma unroll
            for (int j = 0; j < 4; j++)
                mx[j] = fmaxf(mx[j], acc[m][nt][j]);
        #pragma unroll
        for (int j = 0; j < 4; j++)
            #pragma unroll
            for (int o = 1; o < 16; o <<= 1)
                mx[j] = fmaxf(mx[j], __shfl_xor(mx[j], o));
        if ((lane & 15) == 0) {
            int qbase = qb + m * 16 + (lane >> 4) * 4;
            #pragma unroll
            for (int j = 0; j < 4; j++)
                Mpart[((size_t)(n * P + qbase + j)) * 64 + pt] = mx[j];
        }
    }
}

// ---------------- reduce M -> t2, md ----------------
__global__ void k_redM(const float* __restrict__ Mpart, float* __restrict__ t2a,
                       float* __restrict__ mda) {
    int row = blockIdx.x * 256 + threadIdx.x;  // 0..8191
    const f32x4* src = (const f32x4*)(Mpart + (size_t)row * 64);
    float m = -1e30f;
    #pragma unroll
    for (int i = 0; i < 16; i++) {
        f32x4 v = src[i];
        m = fmaxf(m, fmaxf(fmaxf(v[0], v[1]), fmaxf(v[2], v[3])));
    }
    mda[row] = m;
    t2a[row] = 5.f / ((1.f - m) * 0.5f + EPS_F);
}

// ---------------- K5: per-row Z (one block per row, bf16 dist) ----------------
__global__ __launch_bounds__(256) void k_rowz(const __hip_bfloat16* __restrict__ D,
                                              const float* __restrict__ t2a,
                                              const float* __restrict__ mda,
                                              float* __restrict__ rza) {
    int row = blockIdx.x;   // flat n*P+q, 0..8191
    int t = threadIdx.x;
    float t2 = t2a[row], md = mda[row];
    const short8* src = (const short8*)(D + (size_t)row * P);
    float z = 0.f;
    #pragma unroll
    for (int i = 0; i < 2; i++) {
        short8 v = src[t + 256 * i];
        #pragma unroll
        for (int j = 0; j < 8; j++)
            z += __expf(t2 * (bf2f((unsigned short)v[j]) - md));
    }
    #pragma unroll
    for (int o = 32; o > 0; o >>= 1) z += __shfl_xor(z, o);
    __shared__ float redz[4];
    int lane = t & 63, w = t >> 6;
    if (lane == 0) redz[w] = z;
    __syncthreads();
    if (t == 0) rza[row] = 1.f / (redz[0] + redz[1] + redz[2] + redz[3]);
}

// ---------------- K6: colmax partials, 64 rows x 512 cols per block ----------------
__global__ __launch_bounds__(256) void k_colmax(const __hip_bfloat16* __restrict__ D,
                                                const float* __restrict__ t2a,
                                                const float* __restrict__ mda,
                                                const float* __restrict__ rza,
                                                float* __restrict__ Cpart) {
    // grid: x = p-chunk(8 x 512 cols), y = q-seg(64 x 64 rows), z = n(2); block 256
    __shared__ float st2[64], smd[64], srz[64];
    int t = threadIdx.x, lane = t & 63, w = t >> 6;
    int n = blockIdx.z, q0 = blockIdx.y * 64;
    int p0 = blockIdx.x * 512 + lane * 8;
    if (t < 64) {
        st2[t] = t2a[n * P + q0 + t];
        smd[t] = mda[n * P + q0 + t];
        srz[t] = rza[n * P + q0 + t];
    }
    __syncthreads();
    float cmax[8];
    #pragma unroll
    for (int j = 0; j < 8; j++) cmax[j] = 0.f;
    const char* base = (const char*)(D + ((size_t)n * P + q0) * P + p0);
    #pragma unroll 4
    for (int it = 0; it < 16; it++) {
        int r = it * 4 + w;
        short8 v = *(const short8*)(base + (size_t)r * (P * 2));
        float tt = st2[r], mm = smd[r], zz = srz[r];
        #pragma unroll
        for (int j = 0; j < 8; j++) {
            float val = __expf(tt * (bf2f((unsigned short)v[j]) - mm)) * zz;
            cmax[j] = fmaxf(cmax[j], val);
        }
    }
    // waves 0..3 handled disjoint rows; combine across waves via LDS (all 256 threads)
    __shared__ float cred[4][512];
    #pragma unroll
    for (int j = 0; j < 8; j++) cred[w][lane * 8 + j] = cmax[j];
    __syncthreads();
    {
        float* cp = Cpart + ((size_t)(n * 64 + blockIdx.y)) * P + blockIdx.x * 512;
        #pragma unroll
        for (int i = 0; i < 2; i++) {
            int c = t + 256 * i;
            float m0 = fmaxf(fmaxf(cred[0][c], cred[1][c]), fmaxf(cred[2][c], cred[3][c]));
            cp[c] = m0;
        }
    }
}

// ---------------- reduce colmax partials (64 q-segs) ----------------
__global__ void k_colred(const float* __restrict__ Cpart, float* __restrict__ colmax) {
    int np = blockIdx.x * 256 + threadIdx.x;  // flat n*P+p, 0..8191
    int n = np >> 12, p = np & 4095;
    float c = 0.f;
    for (int g = 0; g < 64; g++)
        c = fmaxf(c, Cpart[((size_t)(n * 64 + g)) * P + p]);
    colmax[np] = c;
}

// ---------------- final: -log(mean_p colmax), mean over n ----------------
__global__ void k_final(const float* __restrict__ colmax, float* __restrict__ out) {
    __shared__ float red[256];
    int t = threadIdx.x;
    float cx[NB];
    for (int n = 0; n < NB; n++) {
        float s = 0.f;
        for (int i = t; i < P; i += 256) s += colmax[n * P + i];
        red[t] = s; __syncthreads();
        for (int o = 128; o > 0; o >>= 1) { if (t < o) red[t] += red[t + o]; __syncthreads(); }
        cx[n] = -logf(red[0] * (1.f / (float)P));
        __syncthreads();
    }
    if (t == 0) out[0] = 0.5f * (cx[0] + cx[1]);
}

extern "C" void kernel_launch(void* const* d_in, const int* in_sizes, int n_in,
                              void* d_out, int out_size, void* d_ws, size_t ws_size,
                              hipStream_t stream) {
    const float* fT = (const float*)d_in[0];   // featureT
    const float* fI = (const float*)d_in[1];   // featureI
    float* out = (float*)d_out;

    char* ws = (char*)d_ws;
    size_t off = 0;
    __hip_bfloat16* TI = (__hip_bfloat16*)(ws + off); off += 4194304;
    __hip_bfloat16* TT = (__hip_bfloat16*)(ws + off); off += 4194304;
    __hip_bfloat16* D  = (__hip_bfloat16*)(ws + off); off += (size_t)NB * P * P * 2;  // 67 MiB
    float* Mpart  = (float*)(ws + off); off += (size_t)NB * P * 64 * 4;               // 2 MiB
    float* Cpart  = (float*)(ws + off); off += (size_t)NB * 64 * P * 4;               // 2 MiB
    float* mean   = (float*)(ws + off); off += 1024;
    float* rnormI = (float*)(ws + off); off += 32768;
    float* rnormT = (float*)(ws + off); off += 32768;
    float* t2a    = (float*)(ws + off); off += 32768;
    float* mda    = (float*)(ws + off); off += 32768;
    float* rza    = (float*)(ws + off); off += 32768;
    float* colmax = (float*)(ws + off); off += 32768;

    k_mean<<<256, 256, 0, stream>>>(fT, mean);
    k_norm<<<dim3(64, 2), 256, 0, stream>>>(fI, mean, rnormI);
    k_norm<<<dim3(64, 2), 256, 0, stream>>>(fT, mean, rnormT);
    k_pack<<<dim3(64, 4, 2), 256, 0, stream>>>(fI, mean, rnormI, TI);
    k_pack<<<dim3(64, 4, 2), 256, 0, stream>>>(fT, mean, rnormT, TT);
    k_gemm<<<dim3(32, 32, 2), 256, 0, stream>>>(TI, TT, D, Mpart);
    k_redM<<<32, 256, 0, stream>>>(Mpart, t2a, mda);
    k_rowz<<<8192, 256, 0, stream>>>(D, t2a, mda, rza);
    k_colmax<<<dim3(8, 64, 2), 256, 0, stream>>>(D, t2a, mda, rza, Cpart);
    k_colred<<<32, 256, 0, stream>>>(Cpart, colmax);
    k_final<<<1, 256, 0, stream>>>(colmax, out);
}

// Round 8
// 105.602 us; speedup vs baseline: 1.4603x; 1.1157x over previous
//
#include <hip/hip_runtime.h>
#include <hip/hip_bf16.h>
#include <math.h>

#define NB 2
#define C 256
#define P 4096   // 64*64
#define EPS_F 1e-5f

typedef __attribute__((ext_vector_type(8))) short short8;
typedef __attribute__((ext_vector_type(4))) float f32x4;

__device__ __forceinline__ float bf2f(unsigned short u) {
    union { unsigned int i; float f; } x;
    x.i = ((unsigned int)u) << 16;
    return x.f;
}

// ---------------- K1: per-channel mean of featureT over n,h,w ----------------
__global__ void k_mean(const float* __restrict__ fT, float* __restrict__ mean) {
    int c = blockIdx.x;
    int t = threadIdx.x;
    const float* p0 = fT + (size_t)c * P;          // n=0
    const float* p1 = fT + (size_t)(C + c) * P;    // n=1
    float s = 0.f;
    for (int i = t; i < P; i += 256) s += p0[i] + p1[i];
    __shared__ float red[256];
    red[t] = s; __syncthreads();
    for (int o = 128; o > 0; o >>= 1) { if (t < o) red[t] += red[t + o]; __syncthreads(); }
    if (t == 0) mean[c] = red[0] * (1.f / 8192.f);
}

// ---------------- K2: fused center + L2-norm + transpose-pack to bf16 ----------------
__global__ __launch_bounds__(256) void k_normpack(const float* __restrict__ f,
                                                  const float* __restrict__ mean,
                                                  __hip_bfloat16* __restrict__ out) {
    // grid: x = p-tile(128 tiles of 32 pixels), y = n(2); block 256 = 8 cgrp x 32 pix
    __shared__ float mn[C];
    __shared__ float tile[C][33];   // centered values, +1 pad (33%32==1)
    __shared__ float part[8][32];
    __shared__ float srn[32];
    int t = threadIdx.x;
    mn[t] = mean[t];
    __syncthreads();
    int n = blockIdx.y, p0 = blockIdx.x * 32;
    int pl = t & 31, cg = t >> 5;
    const float* base = f + (size_t)n * C * P + p0 + pl;
    float acc = 0.f;
    #pragma unroll 4
    for (int cc = 0; cc < 32; cc++) {
        int c = cg * 32 + cc;
        float v = base[(size_t)c * P] - mn[c];
        tile[c][pl] = v;
        acc += v * v;
    }
    part[cg][pl] = acc;
    __syncthreads();
    if (t < 32) {
        float s = 0.f;
        #pragma unroll
        for (int g = 0; g < 8; g++) s += part[g][t];
        srn[t] = rsqrtf(s);
    }
    __syncthreads();
    // write out[n][p][c] bf16, 16B per thread per iter
    #pragma unroll
    for (int it = 0; it < 4; it++) {
        int flat = it * 2048 + t * 8;
        int p = flat >> 8;          // 0..31
        int c = flat & 255;
        float rn = srn[p];
        union { __hip_bfloat16 h[8]; short8 s; } u;
        #pragma unroll
        for (int k = 0; k < 8; k++)
            u.h[k] = __float2bfloat16(tile[c + k][p] * rn);
        *(short8*)(out + ((size_t)(n * P + p0 + p)) * C + c) = u.s;
    }
}

// ---------------- staging: one wave stages 32 rows x 32 cols (64B/row) of a tile ----------------
// LDS layout: linear [128 rows][64 B]. Source pre-swizzled by ((row>>1)&3)<<4 so the
// swizzled ds_read_b128 below hits all 8 distinct 16B slots per consecutive 8 lanes.
__device__ __forceinline__ void stage_tile(const __hip_bfloat16* __restrict__ gbase,
                                           __hip_bfloat16* lbuf, int kk, int wid, int lane) {
    #pragma unroll
    for (int j = 0; j < 2; j++) {
        int row = wid * 32 + j * 16 + (lane >> 2);
        int cb = (lane & 3) * 16;
        int scb = cb ^ (((row >> 1) & 3) << 4);
        const char* gp = (const char*)gbase + (size_t)row * (C * 2) + kk * 64 + scb;
        char* lp = (char*)lbuf + (wid * 32 + j * 16) * 64;   // wave-uniform base
        __builtin_amdgcn_global_load_lds(
            (const __attribute__((address_space(1))) void*)gp,
            (__attribute__((address_space(3))) void*)lp, 16, 0, 0);
    }
}

__device__ __forceinline__ short8 ldfrag(const __hip_bfloat16* lbuf, int rloc, int kb) {
    int addr = rloc * 64 + (kb ^ (((rloc >> 1) & 3) << 4));
    return *(const short8*)((const char*)lbuf + addr);
}

// ---------------- K4: fused GEMM: bf16 dist store + row-max partials ----------------
__global__ __launch_bounds__(256) void k_gemm(const __hip_bfloat16* __restrict__ TI,
                                              const __hip_bfloat16* __restrict__ TT,
                                              __hip_bfloat16* __restrict__ D,
                                              float* __restrict__ Mpart) {
    // grid: x = flat tile (1024), z = n(2); 4 waves 2x2 over 128x128, BK=32
    __shared__ __hip_bfloat16 lA[2][128 * 32];
    __shared__ __hip_bfloat16 lB[2][128 * 32];
    int lane = threadIdx.x & 63, wid = threadIdx.x >> 6;
    int wr = wid >> 1, wc = wid & 1;
    int n = blockIdx.z;
    // XCD-aware swizzle: XCD (i&7) owns contiguous swz range -> 4 q-panels/XCD L2
    int i = blockIdx.x;
    int swz = (i & 7) * 128 + (i >> 3);
    int by = swz >> 5, bx = swz & 31;
    const __hip_bfloat16* A = TI + ((size_t)n * P + by * 128) * C;
    const __hip_bfloat16* B = TT + ((size_t)n * P + bx * 128) * C;

    f32x4 acc[4][4];
    #pragma unroll
    for (int m = 0; m < 4; m++)
        #pragma unroll
        for (int nt = 0; nt < 4; nt++)
            acc[m][nt] = (f32x4){0.f, 0.f, 0.f, 0.f};

    int rA = lane & 15;
    int kb = (lane >> 4) * 16;   // byte offset within 64B k-row

    stage_tile(A, lA[0], 0, wid, lane);
    stage_tile(B, lB[0], 0, wid, lane);
    __syncthreads();

    #pragma unroll
    for (int t = 0; t < 8; t++) {
        int cur = t & 1;
        if (t < 7) {
            stage_tile(A, lA[cur ^ 1], t + 1, wid, lane);
            stage_tile(B, lB[cur ^ 1], t + 1, wid, lane);
        }
        short8 a[4], b[4];
        #pragma unroll
        for (int m = 0; m < 4; m++)
            a[m] = ldfrag(lA[cur], wr * 64 + m * 16 + rA, kb);
        #pragma unroll
        for (int nt = 0; nt < 4; nt++)
            b[nt] = ldfrag(lB[cur], wc * 64 + nt * 16 + rA, kb);
        #pragma unroll
        for (int m = 0; m < 4; m++)
            #pragma unroll
            for (int nt = 0; nt < 4; nt++)
                acc[m][nt] = __builtin_amdgcn_mfma_f32_16x16x32_bf16(a[m], b[nt], acc[m][nt], 0, 0, 0);
        __syncthreads();
    }

    // epilogue 1: bf16 dist store (direct, fragment-layout scalar stores)
    int qb = by * 128 + wr * 64;
    int pb = bx * 128 + wc * 64;
    int rj = (lane >> 4) * 4, cl = lane & 15;
    __hip_bfloat16* Dn = D + (size_t)n * P * P;
    #pragma unroll
    for (int m = 0; m < 4; m++)
        #pragma unroll
        for (int nt = 0; nt < 4; nt++)
            #pragma unroll
            for (int j = 0; j < 4; j++)
                Dn[(size_t)(qb + m * 16 + rj + j) * P + pb + nt * 16 + cl] =
                    __float2bfloat16(acc[m][nt][j]);

    // epilogue 2: row-max partials (exact, fp32)
    int pt = bx * 2 + wc;
    #pragma unroll
    for (int m = 0; m < 4; m++) {
        f32x4 mx = acc[m][0];
        #pragma unroll
        for (int nt = 1; nt < 4; nt++)
            #pragma unroll
            for (int j = 0; j < 4; j++)
                mx[j] = fmaxf(mx[j], acc[m][nt][j]);
        #pragma unroll
        for (int j = 0; j < 4; j++)
            #pragma unroll
            for (int o = 1; o < 16; o <<= 1)
                mx[j] = fmaxf(mx[j], __shfl_xor(mx[j], o));
        if ((lane & 15) == 0) {
            int qbase = qb + m * 16 + (lane >> 4) * 4;
            #pragma unroll
            for (int j = 0; j < 4; j++)
                Mpart[((size_t)(n * P + qbase + j)) * 64 + pt] = mx[j];
        }
    }
}

// ---------------- K5: per-row max (from Mpart) + Z; outputs t2, c = -t2*md - logZ ----------------
__global__ __launch_bounds__(256) void k_rowz(const __hip_bfloat16* __restrict__ D,
                                              const float* __restrict__ Mpart,
                                              float* __restrict__ t2a,
                                              float* __restrict__ ca) {
    int row = blockIdx.x;   // flat n*P+q, 0..8191
    int t = threadIdx.x, lane = t & 63, w = t >> 6;
    // row max from the 64 gemm partials (every wave computes it redundantly)
    float m = Mpart[(size_t)row * 64 + lane];
    #pragma unroll
    for (int o = 32; o > 0; o >>= 1) m = fmaxf(m, __shfl_xor(m, o));
    float t2 = 5.f / ((1.f - m) * 0.5f + EPS_F);
    const short8* src = (const short8*)(D + (size_t)row * P);
    float z = 0.f;
    #pragma unroll
    for (int i = 0; i < 2; i++) {
        short8 v = src[t + 256 * i];
        #pragma unroll
        for (int j = 0; j < 8; j++)
            z += __expf(t2 * (bf2f((unsigned short)v[j]) - m));
    }
    #pragma unroll
    for (int o = 32; o > 0; o >>= 1) z += __shfl_xor(z, o);
    __shared__ float redz[4];
    if (lane == 0) redz[w] = z;
    __syncthreads();
    if (t == 0) {
        float zz = redz[0] + redz[1] + redz[2] + redz[3];
        t2a[row] = t2;
        ca[row] = -t2 * m - logf(zz);
    }
}

// ---------------- K6: log-domain colmax partials, 64 rows x 512 cols per block ----------------
// max_q exp(t2*(d-md))/Z == exp(max_q [t2*d + c]); inner loop is fma+max only.
__global__ __launch_bounds__(256) void k_colmax(const __hip_bfloat16* __restrict__ D,
                                                const float* __restrict__ t2a,
                                                const float* __restrict__ ca,
                                                float* __restrict__ Cpart) {
    // grid: x = p-chunk(8 x 512 cols), y = q-seg(64 x 64 rows), z = n(2); block 256
    __shared__ float st2[64], sc[64];
    int t = threadIdx.x, lane = t & 63, w = t >> 6;
    int n = blockIdx.z, q0 = blockIdx.y * 64;
    int p0 = blockIdx.x * 512 + lane * 8;
    if (t < 64) {
        st2[t] = t2a[n * P + q0 + t];
        sc[t]  = ca[n * P + q0 + t];
    }
    __syncthreads();
    float cmax[8];
    #pragma unroll
    for (int j = 0; j < 8; j++) cmax[j] = -1e30f;
    const char* base = (const char*)(D + ((size_t)n * P + q0) * P + p0);
    #pragma unroll 4
    for (int it = 0; it < 16; it++) {
        int r = it * 4 + w;
        short8 v = *(const short8*)(base + (size_t)r * (P * 2));
        float tt = st2[r], cc = sc[r];
        #pragma unroll
        for (int j = 0; j < 8; j++)
            cmax[j] = fmaxf(cmax[j], fmaf(tt, bf2f((unsigned short)v[j]), cc));
    }
    // combine across waves via LDS (all 256 threads write back)
    __shared__ float cred[4][512];
    #pragma unroll
    for (int j = 0; j < 8; j++) cred[w][lane * 8 + j] = cmax[j];
    __syncthreads();
    {
        float* cp = Cpart + ((size_t)(n * 64 + blockIdx.y)) * P + blockIdx.x * 512;
        #pragma unroll
        for (int i = 0; i < 2; i++) {
            int c = t + 256 * i;
            float m0 = fmaxf(fmaxf(cred[0][c], cred[1][c]), fmaxf(cred[2][c], cred[3][c]));
            cp[c] = m0;
        }
    }
}

// ---------------- reduce colmax partials (64 q-segs), exp back from log-domain ----------------
__global__ void k_colred(const float* __restrict__ Cpart, float* __restrict__ colmax) {
    int np = blockIdx.x * 256 + threadIdx.x;  // flat n*P+p, 0..8191
    int n = np >> 12, p = np & 4095;
    float c = -1e30f;
    for (int g = 0; g < 64; g++)
        c = fmaxf(c, Cpart[((size_t)(n * 64 + g)) * P + p]);
    colmax[np] = __expf(c);
}

// ---------------- final: -log(mean_p colmax), mean over n ----------------
__global__ void k_final(const float* __restrict__ colmax, float* __restrict__ out) {
    __shared__ float red[256];
    int t = threadIdx.x;
    float cx[NB];
    for (int n = 0; n < NB; n++) {
        float s = 0.f;
        for (int i = t; i < P; i += 256) s += colmax[n * P + i];
        red[t] = s; __syncthreads();
        for (int o = 128; o > 0; o >>= 1) { if (t < o) red[t] += red[t + o]; __syncthreads(); }
        cx[n] = -logf(red[0] * (1.f / (float)P));
        __syncthreads();
    }
    if (t == 0) out[0] = 0.5f * (cx[0] + cx[1]);
}

extern "C" void kernel_launch(void* const* d_in, const int* in_sizes, int n_in,
                              void* d_out, int out_size, void* d_ws, size_t ws_size,
                              hipStream_t stream) {
    const float* fT = (const float*)d_in[0];   // featureT
    const float* fI = (const float*)d_in[1];   // featureI
    float* out = (float*)d_out;

    char* ws = (char*)d_ws;
    size_t off = 0;
    __hip_bfloat16* TI = (__hip_bfloat16*)(ws + off); off += 4194304;
    __hip_bfloat16* TT = (__hip_bfloat16*)(ws + off); off += 4194304;
    __hip_bfloat16* D  = (__hip_bfloat16*)(ws + off); off += (size_t)NB * P * P * 2;  // 67 MiB
    float* Mpart  = (float*)(ws + off); off += (size_t)NB * P * 64 * 4;               // 2 MiB
    float* Cpart  = (float*)(ws + off); off += (size_t)NB * 64 * P * 4;               // 2 MiB
    float* mean   = (float*)(ws + off); off += 1024;
    float* t2a    = (float*)(ws + off); off += 32768;
    float* ca     = (float*)(ws + off); off += 32768;
    float* colmax = (float*)(ws + off); off += 32768;

    k_mean<<<256, 256, 0, stream>>>(fT, mean);
    k_normpack<<<dim3(128, 2), 256, 0, stream>>>(fI, mean, TI);
    k_normpack<<<dim3(128, 2), 256, 0, stream>>>(fT, mean, TT);
    k_gemm<<<dim3(1024, 1, 2), 256, 0, stream>>>(TI, TT, D, Mpart);
    k_rowz<<<8192, 256, 0, stream>>>(D, Mpart, t2a, ca);
    k_colmax<<<dim3(8, 64, 2), 256, 0, stream>>>(D, t2a, ca, Cpart);
    k_colred<<<32, 256, 0, stream>>>(Cpart, colmax);
    k_final<<<1, 256, 0, stream>>>(colmax, out);
}